// Round 1
// baseline (732.306 us; speedup 1.0000x reference)
//
#include <hip/hip_runtime.h>

#define MAXC 1000
#define DSUB 32
#define SCATTER_THREADS 1024
#define NUM_CHUNKS 32

// ---------------------------------------------------------------------------
// Kernel 1: segment-sum scatter with LDS privatization.
// Each block owns a DSUB=32-dim slice of ALL C classes in LDS (125 KB) plus a
// count histogram (blockIdx.y==0 blocks only). Streams a contiguous sample
// chunk, LDS-atomicAdds per element, then flushes to global with f32 atomics.
// ---------------------------------------------------------------------------
__global__ __launch_bounds__(SCATTER_THREADS) void scatter_kernel(
    const float* __restrict__ x, const int* __restrict__ l,
    float* __restrict__ sums, float* __restrict__ counts,
    int B, int D, int C, int chunk)
{
    __shared__ float lsum[MAXC * DSUB];
    __shared__ float lcnt[MAXC];

    const bool doCount = (blockIdx.y == 0);
    for (int i = threadIdx.x; i < MAXC * DSUB; i += SCATTER_THREADS) lsum[i] = 0.f;
    for (int i = threadIdx.x; i < MAXC; i += SCATTER_THREADS) lcnt[i] = 0.f;
    __syncthreads();

    const int dbase = blockIdx.y * DSUB;
    const int d    = threadIdx.x & (DSUB - 1);
    const int srel = threadIdx.x >> 5;              // 0..31
    const int SPI  = SCATTER_THREADS / DSUB;        // 32 samples in flight

    const int s0 = blockIdx.x * chunk;
    const int s1 = min(B, s0 + chunk);

    int s = s0 + srel;
    // main loop, unrolled x4 so loads batch ahead of the LDS atomics
    for (; s + 3 * SPI < s1; s += 4 * SPI) {
        int c0 = l[s];
        int c1 = l[s + SPI];
        int c2 = l[s + 2 * SPI];
        int c3 = l[s + 3 * SPI];
        float v0 = x[(size_t)s * D + dbase + d];
        float v1 = x[(size_t)(s + SPI) * D + dbase + d];
        float v2 = x[(size_t)(s + 2 * SPI) * D + dbase + d];
        float v3 = x[(size_t)(s + 3 * SPI) * D + dbase + d];
        atomicAdd(&lsum[c0 * DSUB + d], v0);
        atomicAdd(&lsum[c1 * DSUB + d], v1);
        atomicAdd(&lsum[c2 * DSUB + d], v2);
        atomicAdd(&lsum[c3 * DSUB + d], v3);
        if (doCount && d == 0) {
            atomicAdd(&lcnt[c0], 1.f);
            atomicAdd(&lcnt[c1], 1.f);
            atomicAdd(&lcnt[c2], 1.f);
            atomicAdd(&lcnt[c3], 1.f);
        }
    }
    for (; s < s1; s += SPI) {
        int c = l[s];
        float v = x[(size_t)s * D + dbase + d];
        atomicAdd(&lsum[c * DSUB + d], v);
        if (doCount && d == 0) atomicAdd(&lcnt[c], 1.f);
    }
    __syncthreads();

    // flush LDS partials to global
    for (int i = threadIdx.x; i < C * DSUB; i += SCATTER_THREADS) {
        float v = lsum[i];
        if (v != 0.f)
            atomicAdd(&sums[(size_t)(i / DSUB) * D + dbase + (i & (DSUB - 1))], v);
    }
    if (doCount) {
        for (int i = threadIdx.x; i < C; i += SCATTER_THREADS) {
            float v = lcnt[i];
            if (v != 0.f) atomicAdd(&counts[i], v);
        }
    }
}

// ---------------------------------------------------------------------------
// block-wide sum over 256 threads (4 waves); result broadcast to all threads
// ---------------------------------------------------------------------------
__device__ __forceinline__ float block_reduce_sum_256(float v, float* sbuf) {
    #pragma unroll
    for (int o = 32; o > 0; o >>= 1) v += __shfl_down(v, o, 64);
    __syncthreads();                       // protect sbuf across repeated calls
    if ((threadIdx.x & 63) == 0) sbuf[threadIdx.x >> 6] = v;
    __syncthreads();
    return sbuf[0] + sbuf[1] + sbuf[2] + sbuf[3];
}

// ---------------------------------------------------------------------------
// Kernel 2: per-class momentum update + L2 renorm + squared distance.
// One block (256 threads) per class; thread t owns dim t (D == 256).
// ---------------------------------------------------------------------------
__global__ __launch_bounds__(256) void update_kernel(
    const float* __restrict__ sums, const float* __restrict__ counts,
    const float* __restrict__ cimg, const float* __restrict__ cskt,
    float* __restrict__ sq_out, float* __restrict__ pres_out, int D)
{
    __shared__ float sbuf[4];
    const int c = blockIdx.x;
    const int t = threadIdx.x;

    const float cnt = counts[c];
    const bool present = cnt > 0.5f;

    float upd = 0.f, ci = 0.f, cs = 0.f;
    if (t < D) {
        const size_t idx = (size_t)c * D + t;
        ci = cimg[idx];
        cs = cskt[idx];
        const float mean = sums[idx] / fmaxf(cnt, 1.f);
        upd = ci * 0.9f + mean * 0.1f;
    }
    const float n2 = block_reduce_sum_256(upd * upd, sbuf);
    const float inv = 1.0f / sqrtf(n2);
    const float newv = present ? upd * inv : ci;
    const float df = (t < D) ? (newv - cs) : 0.f;
    const float sq = block_reduce_sum_256(df * df, sbuf);
    if (t == 0) {
        sq_out[c]   = present ? sq : 0.f;
        pres_out[c] = present ? 1.f : 0.f;
    }
}

// ---------------------------------------------------------------------------
// Kernel 3: final reduction over classes -> scalar loss
// ---------------------------------------------------------------------------
__global__ __launch_bounds__(256) void finalize_kernel(
    const float* __restrict__ sq, const float* __restrict__ pres,
    float* __restrict__ out, int C)
{
    __shared__ float sbuf[4];
    float ls = 0.f, np = 0.f;
    for (int i = threadIdx.x; i < C; i += 256) {
        ls += sq[i];
        np += pres[i];
    }
    ls = block_reduce_sum_256(ls, sbuf);
    np = block_reduce_sum_256(np, sbuf);
    if (threadIdx.x == 0) out[0] = ls / fmaxf(np, 1.f);
}

extern "C" void kernel_launch(void* const* d_in, const int* in_sizes, int n_in,
                              void* d_out, int out_size, void* d_ws, size_t ws_size,
                              hipStream_t stream) {
    const float* x    = (const float*)d_in[0];
    const int*   l    = (const int*)d_in[1];
    const float* cimg = (const float*)d_in[2];
    const float* cskt = (const float*)d_in[3];

    const int B = in_sizes[1];
    const int D = in_sizes[0] / B;     // 256
    const int C = in_sizes[2] / D;     // 1000

    float* ws     = (float*)d_ws;
    float* counts = ws;                        // [C]
    float* sums   = ws + C;                    // [C*D]
    float* sq     = ws + C + (size_t)C * D;    // [C]
    float* pres   = sq + C;                    // [C]

    // zero the accumulators (counts + sums); sq/pres are fully overwritten
    hipMemsetAsync(ws, 0, sizeof(float) * (C + (size_t)C * D), stream);

    const int chunk = (B + NUM_CHUNKS - 1) / NUM_CHUNKS;
    dim3 grid(NUM_CHUNKS, D / DSUB);           // 32 x 8 = 256 blocks (1/CU)
    scatter_kernel<<<grid, SCATTER_THREADS, 0, stream>>>(x, l, sums, counts, B, D, C, chunk);

    update_kernel<<<C, 256, 0, stream>>>(sums, counts, cimg, cskt, sq, pres, D);

    finalize_kernel<<<1, 256, 0, stream>>>(sq, pres, (float*)d_out, C);
}

// Round 2
// 139.548 us; speedup vs baseline: 5.2477x; 5.2477x over previous
//
#include <hip/hip_runtime.h>

#define MAXC    1000
#define DSUB    32
#define LSTR    33          // padded class stride in LDS (banks scatter per class)
#define THREADS 1024
#define NCHUNK  32
#define FIXS    1048576.0f  // 2^20 fixed-point scale
#define INVFIXS (1.0f / 1048576.0f)

// ---------------------------------------------------------------------------
// Kernel 1: segment-sum scatter, LDS-privatized in int32 fixed point.
// Block (chunkIdx, dimGroup) owns a DSUB=32-dim slice of all C classes.
// MODE 0: flush to per-chunk partial buffers with plain stores (no atomics).
// MODE 1: flush with native global int atomics (small-ws fallback).
// ---------------------------------------------------------------------------
template <int MODE>
__global__ __launch_bounds__(THREADS) void scatter_kernel(
    const float* __restrict__ x, const int* __restrict__ l,
    float* __restrict__ part, float* __restrict__ cnt_part,
    int* __restrict__ sums_i, int* __restrict__ cnt_i,
    int B, int D, int C, int chunk)
{
    __shared__ int lsum[MAXC * LSTR];
    __shared__ int lcnt[MAXC];

    for (int i = threadIdx.x; i < MAXC * LSTR; i += THREADS) lsum[i] = 0;
    for (int i = threadIdx.x; i < MAXC; i += THREADS) lcnt[i] = 0;
    __syncthreads();

    const bool doCount = (blockIdx.y == 0);
    const int dbase = blockIdx.y * DSUB;
    const int q     = threadIdx.x & 7;       // dim-quad within the 32-dim slice
    const int srel  = threadIdx.x >> 3;      // 0..127
    const int STEP  = THREADS >> 3;          // 128 samples in flight per step
    const int DV    = D >> 2;                // row stride in float4
    const int qb    = (dbase >> 2) + q;

    const float4* __restrict__ x4 = (const float4*)x;

    const int s0 = blockIdx.x * chunk;
    const int s1 = min(B, s0 + chunk);

    int s = s0 + srel;
    for (; s + 3 * STEP < s1; s += 4 * STEP) {
        int c0 = l[s];
        int c1 = l[s + STEP];
        int c2 = l[s + 2 * STEP];
        int c3 = l[s + 3 * STEP];
        float4 v0 = x4[(size_t)s * DV + qb];
        float4 v1 = x4[(size_t)(s + STEP) * DV + qb];
        float4 v2 = x4[(size_t)(s + 2 * STEP) * DV + qb];
        float4 v3 = x4[(size_t)(s + 3 * STEP) * DV + qb];
        const int b0 = c0 * LSTR + (q << 2);
        const int b1 = c1 * LSTR + (q << 2);
        const int b2 = c2 * LSTR + (q << 2);
        const int b3 = c3 * LSTR + (q << 2);
        atomicAdd(&lsum[b0 + 0], __float2int_rn(v0.x * FIXS));
        atomicAdd(&lsum[b0 + 1], __float2int_rn(v0.y * FIXS));
        atomicAdd(&lsum[b0 + 2], __float2int_rn(v0.z * FIXS));
        atomicAdd(&lsum[b0 + 3], __float2int_rn(v0.w * FIXS));
        atomicAdd(&lsum[b1 + 0], __float2int_rn(v1.x * FIXS));
        atomicAdd(&lsum[b1 + 1], __float2int_rn(v1.y * FIXS));
        atomicAdd(&lsum[b1 + 2], __float2int_rn(v1.z * FIXS));
        atomicAdd(&lsum[b1 + 3], __float2int_rn(v1.w * FIXS));
        atomicAdd(&lsum[b2 + 0], __float2int_rn(v2.x * FIXS));
        atomicAdd(&lsum[b2 + 1], __float2int_rn(v2.y * FIXS));
        atomicAdd(&lsum[b2 + 2], __float2int_rn(v2.z * FIXS));
        atomicAdd(&lsum[b2 + 3], __float2int_rn(v2.w * FIXS));
        atomicAdd(&lsum[b3 + 0], __float2int_rn(v3.x * FIXS));
        atomicAdd(&lsum[b3 + 1], __float2int_rn(v3.y * FIXS));
        atomicAdd(&lsum[b3 + 2], __float2int_rn(v3.z * FIXS));
        atomicAdd(&lsum[b3 + 3], __float2int_rn(v3.w * FIXS));
        if (doCount && q == 0) {
            atomicAdd(&lcnt[c0], 1);
            atomicAdd(&lcnt[c1], 1);
            atomicAdd(&lcnt[c2], 1);
            atomicAdd(&lcnt[c3], 1);
        }
    }
    for (; s < s1; s += STEP) {
        int c = l[s];
        float4 v = x4[(size_t)s * DV + qb];
        const int b = c * LSTR + (q << 2);
        atomicAdd(&lsum[b + 0], __float2int_rn(v.x * FIXS));
        atomicAdd(&lsum[b + 1], __float2int_rn(v.y * FIXS));
        atomicAdd(&lsum[b + 2], __float2int_rn(v.z * FIXS));
        atomicAdd(&lsum[b + 3], __float2int_rn(v.w * FIXS));
        if (doCount && q == 0) atomicAdd(&lcnt[c], 1);
    }
    __syncthreads();

    if (MODE == 0) {
        float* myp = part + (size_t)blockIdx.x * C * D + dbase;
        for (int i = threadIdx.x; i < C * DSUB; i += THREADS) {
            const int c = i >> 5, d = i & (DSUB - 1);
            myp[(size_t)c * D + d] = (float)lsum[c * LSTR + d] * INVFIXS;
        }
        if (doCount)
            for (int i = threadIdx.x; i < C; i += THREADS)
                cnt_part[(size_t)blockIdx.x * C + i] = (float)lcnt[i];
    } else {
        for (int i = threadIdx.x; i < C * DSUB; i += THREADS) {
            const int c = i >> 5, d = i & (DSUB - 1);
            const int v = lsum[c * LSTR + d];
            if (v) atomicAdd(&sums_i[(size_t)c * D + dbase + d], v);
        }
        if (doCount)
            for (int i = threadIdx.x; i < C; i += THREADS) {
                const int v = lcnt[i];
                if (v) atomicAdd(&cnt_i[i], v);
            }
    }
}

// ---------------------------------------------------------------------------
// block-wide sum over 256 threads (4 waves); result broadcast to all threads
// ---------------------------------------------------------------------------
__device__ __forceinline__ float block_reduce_sum_256(float v, float* sbuf) {
    #pragma unroll
    for (int o = 32; o > 0; o >>= 1) v += __shfl_down(v, o, 64);
    __syncthreads();                 // protect sbuf across repeated calls
    if ((threadIdx.x & 63) == 0) sbuf[threadIdx.x >> 6] = v;
    __syncthreads();
    return sbuf[0] + sbuf[1] + sbuf[2] + sbuf[3];
}

// ---------------------------------------------------------------------------
// Kernel 2: reduce partials + per-class momentum update + renorm + sq dist.
// One block (256 threads == D) per class.
// ---------------------------------------------------------------------------
template <int MODE>
__global__ __launch_bounds__(256) void update_kernel(
    const float* __restrict__ part, const float* __restrict__ cnt_part,
    const int* __restrict__ sums_i, const int* __restrict__ cnt_i,
    const float* __restrict__ cimg, const float* __restrict__ cskt,
    float* __restrict__ sq_out, float* __restrict__ pres_out, int C, int D)
{
    __shared__ float sbuf[4];
    __shared__ float cshare;
    const int c = blockIdx.x;
    const int t = threadIdx.x;

    float ssum, cnt;
    if (MODE == 0) {
        ssum = 0.f;
        const float* pc = part + (size_t)c * D + t;
        #pragma unroll
        for (int k = 0; k < NCHUNK; ++k) ssum += pc[(size_t)k * C * D];
        if (t < NCHUNK) {
            float cv = cnt_part[(size_t)t * C + c];
            #pragma unroll
            for (int o = NCHUNK / 2; o > 0; o >>= 1) cv += __shfl_down(cv, o, NCHUNK);
            if (t == 0) cshare = cv;
        }
        __syncthreads();
        cnt = cshare;
    } else {
        ssum = (float)sums_i[(size_t)c * D + t] * INVFIXS;
        if (t == 0) cshare = (float)cnt_i[c];
        __syncthreads();
        cnt = cshare;
    }

    const bool present = cnt > 0.5f;
    const size_t idx = (size_t)c * D + t;
    const float ci = cimg[idx];
    const float cs = cskt[idx];
    const float mean = ssum / fmaxf(cnt, 1.f);
    const float upd = ci * 0.9f + mean * 0.1f;
    const float n2 = block_reduce_sum_256(upd * upd, sbuf);
    const float inv = 1.0f / sqrtf(n2);
    const float newv = present ? upd * inv : ci;
    const float df = newv - cs;
    const float sq = block_reduce_sum_256(df * df, sbuf);
    if (t == 0) {
        sq_out[c]   = present ? sq : 0.f;
        pres_out[c] = present ? 1.f : 0.f;
    }
}

// ---------------------------------------------------------------------------
// Kernel 3: final reduction over classes -> scalar loss
// ---------------------------------------------------------------------------
__global__ __launch_bounds__(256) void finalize_kernel(
    const float* __restrict__ sq, const float* __restrict__ pres,
    float* __restrict__ out, int C)
{
    __shared__ float sbuf[4];
    float ls = 0.f, np = 0.f;
    for (int i = threadIdx.x; i < C; i += 256) {
        ls += sq[i];
        np += pres[i];
    }
    ls = block_reduce_sum_256(ls, sbuf);
    np = block_reduce_sum_256(np, sbuf);
    if (threadIdx.x == 0) out[0] = ls / fmaxf(np, 1.f);
}

extern "C" void kernel_launch(void* const* d_in, const int* in_sizes, int n_in,
                              void* d_out, int out_size, void* d_ws, size_t ws_size,
                              hipStream_t stream) {
    const float* x    = (const float*)d_in[0];
    const int*   l    = (const int*)d_in[1];
    const float* cimg = (const float*)d_in[2];
    const float* cskt = (const float*)d_in[3];

    const int B = in_sizes[1];
    const int D = in_sizes[0] / B;     // 256
    const int C = in_sizes[2] / D;     // 1000

    const size_t partElems = (size_t)NCHUNK * C * D;     // 8.19M floats
    const size_t cntElems  = (size_t)NCHUNK * C;
    const size_t need0 = (partElems + cntElems + 2 * (size_t)C) * sizeof(float);

    const int chunk = (B + NCHUNK - 1) / NCHUNK;
    dim3 grid(NCHUNK, D / DSUB);       // 32 x 8 = 256 blocks (1/CU)

    if (ws_size >= need0) {
        // partials path: zero global atomics, no memset needed
        float* part     = (float*)d_ws;
        float* cnt_part = part + partElems;
        float* sq       = cnt_part + cntElems;
        float* pres     = sq + C;
        scatter_kernel<0><<<grid, THREADS, 0, stream>>>(
            x, l, part, cnt_part, nullptr, nullptr, B, D, C, chunk);
        update_kernel<0><<<C, 256, 0, stream>>>(
            part, cnt_part, nullptr, nullptr, cimg, cskt, sq, pres, C, D);
        finalize_kernel<<<1, 256, 0, stream>>>(sq, pres, (float*)d_out, C);
    } else {
        // fallback: native int32 global atomics
        int*   sums_i = (int*)d_ws;
        int*   cnt_i  = sums_i + (size_t)C * D;
        float* sq     = (float*)(cnt_i + C);
        float* pres   = sq + C;
        hipMemsetAsync(d_ws, 0, sizeof(int) * ((size_t)C * D + C), stream);
        scatter_kernel<1><<<grid, THREADS, 0, stream>>>(
            x, l, nullptr, nullptr, sums_i, cnt_i, B, D, C, chunk);
        update_kernel<1><<<C, 256, 0, stream>>>(
            nullptr, nullptr, sums_i, cnt_i, cimg, cskt, sq, pres, C, D);
        finalize_kernel<<<1, 256, 0, stream>>>(sq, pres, (float*)d_out, C);
    }
}